// Round 11
// baseline (462.477 us; speedup 1.0000x reference)
//
#include <hip/hip_runtime.h>
#include <math.h>

#define NROWS 65536
#define D 256
#define K 1024
#define CAP 16
#define EPS 2e-3f

// d_out offsets (floats)
#define OFF_Q     0
#define OFF_LOSS  16777216
#define OFF_IDX   16777217
#define OFF_CS    16842753
#define OFF_EMAW  16843777
#define OFF_UPD   17105921

// ws offsets (bytes)
#define WS_HIST     0          // 1024 int   (memset 0)
#define WS_OFFS     266240     // 1024 int
#define WS_CURS     270336     // 1024 int
#define WS_IDX      274432     // 65536 int
#define WS_ROWIDS   536576     // 65536 int (k_fill output; aliased as wrows earlier)
#define WS_WROWS    536576     //   alias: worklist rows (dead before k_fill)
#define WS_SQX      798720     // 65536 f32
#define WS_SQE      1060864    // 1024 f32
#define WS_DW       1064960    // 262144 f32 (k_dw output; aliased earlier:)
#define WS_PACK     1064960    //   alias: 65536 u64 (memset 0xFF; dead before k_dw)
#define WS_GCNT     1589264    //   alias: [0]=row count, [1]=pair count (memset 0)
#define WS_LOSSP    2113536    // 1024 double
#define WS_EBT      2121728    // 8*1024*32 ushort (bf16, k-chunk-major)
#define WS_PLIST    2646016    // 65536*16 u32 pair list (ends 6840320)

typedef __attribute__((ext_vector_type(8))) short short8;
typedef __attribute__((ext_vector_type(8))) unsigned short ushort8;
typedef __attribute__((ext_vector_type(4))) float f32x4;

__device__ __forceinline__ unsigned short f2b(float f) {   // RNE f32->bf16
    unsigned u = __builtin_bit_cast(unsigned, f);
    return (unsigned short)((u + 0x7fffu + ((u >> 16) & 1u)) >> 16);
}

// ---------------- K0: row sum-of-squares (used for sqe only now) ----------------
__global__ __launch_bounds__(256) void k_sq(const float* __restrict__ a_,
                                            float* __restrict__ dst, int n)
{
#pragma clang fp contract(off)
    int r = blockIdx.x * 256 + threadIdx.x;
    if (r >= n) return;
    const float4* a4 = (const float4*)(a_ + (size_t)r * 256);
    float h[2];
#pragma unroll
    for (int hh = 0; hh < 2; ++hh) {
        float p[4][16];
#pragma unroll
        for (int pr = 0; pr < 4; ++pr) {
#pragma unroll
            for (int m = 0; m < 4; ++m) {
                float4 u = a4[hh * 32 + (2 * pr) * 4 + m];
                float4 v = a4[hh * 32 + (2 * pr + 1) * 4 + m];
                p[pr][4 * m + 0] = u.x * u.x + v.x * v.x;
                p[pr][4 * m + 1] = u.y * u.y + v.y * v.y;
                p[pr][4 * m + 2] = u.z * u.z + v.z * v.z;
                p[pr][4 * m + 3] = u.w * u.w + v.w * v.w;
            }
        }
        float V[16];
#pragma unroll
        for (int l = 0; l < 16; ++l) V[l] = (p[0][l] + p[1][l]) + (p[2][l] + p[3][l]);
        float t[8];
#pragma unroll
        for (int l = 0; l < 8; ++l) t[l] = V[l] + V[l + 8];
        float u2[4];
#pragma unroll
        for (int l = 0; l < 4; ++l) u2[l] = t[l] + t[l + 4];
        h[hh] = (u2[0] + u2[2]) + (u2[1] + u2[3]);
    }
    dst[r] = h[0] + h[1];
}

// ---------------- K0b: convert codebook to bf16, k-chunk-major [8][1024][32] ----------------
__global__ __launch_bounds__(256) void k_cvt(const float* __restrict__ ew,
                                             unsigned short* __restrict__ ebt)
{
    int t = blockIdx.x * 256 + threadIdx.x;   // 0..8191
    int code = t >> 3, kc = t & 7;
    const float4* src = (const float4*)&ew[(size_t)code * 256 + kc * 32];
    unsigned short* dst = &ebt[((size_t)kc * 1024 + code) * 32];
#pragma unroll
    for (int j = 0; j < 8; ++j) {
        float4 v = src[j];
        ushort4 o;
        o.x = f2b(v.x); o.y = f2b(v.y); o.z = f2b(v.z); o.w = f2b(v.w);
        *(ushort4*)&dst[j * 4] = o;
    }
}

// ---------------- K1: MFMA bf16 screen + fused sqx + n==1 fast path + pair list ----------------
__global__ __launch_bounds__(512) void k_screen(
    const float* __restrict__ x, const unsigned short* __restrict__ ebt,
    const float* __restrict__ sqe, float* __restrict__ sqx_out,
    int* __restrict__ idx_out, float* __restrict__ idxf_out,
    int* __restrict__ hist, int* __restrict__ wrows, int* __restrict__ gc,
    unsigned int* __restrict__ plist)
{
    __shared__ unsigned short xs[64][264];   // bf16, full K
    __shared__ unsigned short es[256][56];   // bf16, 32-k chunk
    __shared__ float red[64][4];
    __shared__ int lcnt[64];
    __shared__ int scand[64][CAP];

    const int tid = threadIdx.x;
    const int w = tid >> 6, l = tid & 63;
    const int wm = w >> 2, wn = w & 3;
    const int row0 = blockIdx.x * 64;

    if (tid < 64) lcnt[tid] = 0;

    // stage x tile (f32 -> bf16) + fused numpy-pairwise sum-of-squares
    {
        const int row = tid >> 3, kq8 = tid & 7;
        const float4* src = (const float4*)&x[(size_t)(row0 + row) * 256 + kq8 * 32];
        float4 f[8];
#pragma unroll
        for (int j = 0; j < 8; ++j) f[j] = src[j];
#pragma unroll
        for (int j = 0; j < 8; ++j) {
            ushort4 o;
            o.x = f2b(f[j].x); o.y = f2b(f[j].y); o.z = f2b(f[j].z); o.w = f2b(f[j].w);
            *(ushort4*)&xs[row][kq8 * 32 + j * 4] = o;
        }
        // partial p[l] = A[l]^2 + B[l]^2 (A=floats 0..15, B=16..31 of this chunk)
        float p[16];
#pragma unroll
        for (int m = 0; m < 4; ++m) {
            p[4*m+0] = f[m].x * f[m].x + f[m+4].x * f[m+4].x;
            p[4*m+1] = f[m].y * f[m].y + f[m+4].y * f[m+4].y;
            p[4*m+2] = f[m].z * f[m].z + f[m+4].z * f[m+4].z;
            p[4*m+3] = f[m].w * f[m].w + f[m+4].w * f[m+4].w;
        }
        // cross-lane tree over the 8-thread row group (IEEE add commutative -> bit-exact)
        float V[16];
#pragma unroll
        for (int l2 = 0; l2 < 16; ++l2) {
            float q = p[l2] + __shfl_xor(p[l2], 1);
            V[l2] = q + __shfl_xor(q, 2);
        }
        float t8[8];
#pragma unroll
        for (int l2 = 0; l2 < 8; ++l2) t8[l2] = V[l2] + V[l2 + 8];
        float u4[4];
#pragma unroll
        for (int l2 = 0; l2 < 4; ++l2) u4[l2] = t8[l2] + t8[l2 + 4];
        float h = (u4[0] + u4[2]) + (u4[1] + u4[3]);
        float sq = h + __shfl_xor(h, 4);
        if (kq8 == 0) sqx_out[row0 + row] = sq;
    }

#pragma unroll 1
    for (int ct = 0; ct < 4; ++ct) {
        f32x4 acc[2][4];
#pragma unroll
        for (int mt = 0; mt < 2; ++mt)
#pragma unroll
            for (int nt = 0; nt < 4; ++nt) acc[mt][nt] = (f32x4)0.f;

#pragma unroll 1
        for (int kc = 0; kc < 8; ++kc) {
            __syncthreads();
            {   // stage e chunk: 256 codes x 32 k bf16 = 8192 ushorts; 16/thread
                const int cc = tid >> 1, part = tid & 1;
                const unsigned short* s =
                    &ebt[((size_t)kc * 1024 + ct * 256 + cc) * 32 + part * 16];
                *(ushort8*)&es[cc][part * 16 + 0] = *(const ushort8*)&s[0];
                *(ushort8*)&es[cc][part * 16 + 8] = *(const ushort8*)&s[8];
            }
            __syncthreads();
            short8 a[2], b[4];
#pragma unroll
            for (int mt = 0; mt < 2; ++mt)
                a[mt] = *(const short8*)&xs[wm * 32 + mt * 16 + (l & 15)][kc * 32 + (l >> 4) * 8];
#pragma unroll
            for (int nt = 0; nt < 4; ++nt)
                b[nt] = *(const short8*)&es[wn * 64 + nt * 16 + (l & 15)][(l >> 4) * 8];
#pragma unroll
            for (int mt = 0; mt < 2; ++mt)
#pragma unroll
                for (int nt = 0; nt < 4; ++nt)
                    acc[mt][nt] = __builtin_amdgcn_mfma_f32_16x16x32_bf16(
                        a[mt], b[nt], acc[mt][nt], 0, 0, 0);
        }

        float sev[4];
#pragma unroll
        for (int nt = 0; nt < 4; ++nt)
            sev[nt] = sqe[ct * 256 + wn * 64 + nt * 16 + (l & 15)];

#pragma unroll
        for (int mt = 0; mt < 2; ++mt)
#pragma unroll
            for (int q = 0; q < 4; ++q) {
                const int rw = wm * 32 + mt * 16 + (l >> 4) * 4 + q;
                float v = 3.4e38f;
#pragma unroll
                for (int nt = 0; nt < 4; ++nt)
                    v = fminf(v, sev[nt] - 2.0f * acc[mt][nt][q]);
#pragma unroll
                for (int m = 1; m < 16; m <<= 1) v = fminf(v, __shfl_xor(v, m));
                if ((l & 15) == 0) red[rw][wn] = v;
            }
        __syncthreads();
#pragma unroll
        for (int mt = 0; mt < 2; ++mt)
#pragma unroll
            for (int q = 0; q < 4; ++q) {
                const int rw = wm * 32 + mt * 16 + (l >> 4) * 4 + q;
                const float rm = fminf(fminf(red[rw][0], red[rw][1]),
                                       fminf(red[rw][2], red[rw][3])) + EPS;
#pragma unroll
                for (int nt = 0; nt < 4; ++nt) {
                    float s = sev[nt] - 2.0f * acc[mt][nt][q];
                    if (s <= rm) {
                        int c = ct * 256 + wn * 64 + nt * 16 + (l & 15);
                        int slot = atomicAdd(&lcnt[rw], 1);
                        if (slot < CAP) scand[rw][slot] = c;
                    }
                }
            }
        __syncthreads();
    }
    if (tid < 64) {
        const int row = row0 + tid;
        const int n = lcnt[tid];
        if (n == 1) {
            const int c = scand[tid][0];
            idx_out[row] = c;
            idxf_out[row] = (float)c;
            atomicAdd(&hist[c], 1);
        } else {
            int p0 = atomicAdd(&gc[0], 1);
            wrows[p0] = row;
            if (n <= CAP) {
                int pb = atomicAdd(&gc[1], n);
                for (int s = 0; s < n; ++s)
                    plist[pb + s] = ((unsigned)row << 10) | (unsigned)scand[tid][s];
            } else {   // overflow (practically never): CAP strided-scan tasks
                int pb = atomicAdd(&gc[1], CAP);
                for (int s = 0; s < CAP; ++s)
                    plist[pb + s] = (1u << 30) | ((unsigned)row << 10) | (unsigned)s;
            }
        }
    }
}

// ---------------- K1b: 16-lanes-per-pair exact rescore from LDS ----------------
__global__ __launch_bounds__(256) void k_rescore(
    const float* __restrict__ x, const float* __restrict__ ew,
    const float* __restrict__ sqx, const float* __restrict__ sqe,
    const unsigned int* __restrict__ plist, const int* __restrict__ gc,
    unsigned long long* __restrict__ packed)
{
#pragma clang fp contract(off)
    __shared__ __align__(16) float xbuf[16][264];
    __shared__ __align__(16) float ebuf[16][264];
    const int tid = threadIdx.x;
    const int g = tid >> 4, l16 = tid & 15;
    const int npairs = gc[1];
    const float4* __restrict__ X4 = (const float4*)x;
    const float4* __restrict__ E4 = (const float4*)ew;

    for (int base = blockIdx.x * 16; base < npairs; base += gridDim.x * 16) {
        const int p = base + g;
        const bool valid = p < npairs;
        unsigned v = valid ? plist[p] : 0u;
        const int flg = (int)(v >> 30);
        const int row = (int)((v >> 10) & 0xFFFFu);
        const int c = (int)(v & 0x3FFu);
        if (valid) {
#pragma unroll
            for (int j = 0; j < 4; ++j) {
                float4 xv = X4[(size_t)row * 64 + j * 16 + l16];
                *(float4*)&xbuf[g][(j * 16 + l16) * 4] = xv;
            }
            if (!flg) {
#pragma unroll
                for (int j = 0; j < 4; ++j) {
                    float4 ev = E4[(size_t)c * 64 + j * 16 + l16];
                    *(float4*)&ebuf[g][(j * 16 + l16) * 4] = ev;
                }
            }
        }
        __syncthreads();
        if (valid && !flg) {
            // exact reference chain: single f32 acc, fmaf over k ascending
            float acc = 0.f;
#pragma unroll
            for (int kq = 0; kq < 64; ++kq) {
                const float4 a = *(const float4*)&xbuf[g][kq * 4];
                const float4 b = *(const float4*)&ebuf[g][kq * 4];
                acc = __builtin_fmaf(a.x, b.x, acc);
                acc = __builtin_fmaf(a.y, b.y, acc);
                acc = __builtin_fmaf(a.z, b.z, acc);
                acc = __builtin_fmaf(a.w, b.w, acc);
            }
            const float d = (sqx[row] - 2.0f * acc) + sqe[c];
            if (l16 == 0) {
                unsigned long long key =
                    ((unsigned long long)__builtin_bit_cast(unsigned, d) << 32) | (unsigned)c;
                atomicMin(&packed[row], key);
            }
        } else if (valid) {
            // overflow fallback: codes ≡ c (mod CAP), split across 16 lanes
            float bd = 3.4e38f; int bc = 0x7fffffff;
            const float sxr = sqx[row];
            for (int c2 = c + CAP * l16; c2 < K; c2 += CAP * 16) {
                const float4* er = &E4[(size_t)c2 * 64];
                float acc = 0.f;
#pragma unroll
                for (int kq = 0; kq < 64; ++kq) {
                    const float4 a = *(const float4*)&xbuf[g][kq * 4];
                    const float4 b = er[kq];
                    acc = __builtin_fmaf(a.x, b.x, acc);
                    acc = __builtin_fmaf(a.y, b.y, acc);
                    acc = __builtin_fmaf(a.z, b.z, acc);
                    acc = __builtin_fmaf(a.w, b.w, acc);
                }
                float d = (sxr - 2.0f * acc) + sqe[c2];
                if (d < bd || (d == bd && c2 < bc)) { bd = d; bc = c2; }
            }
#pragma unroll
            for (int m = 1; m < 16; m <<= 1) {
                float od = __shfl_xor(bd, m);
                int   oc = __shfl_xor(bc, m);
                if (od < bd || (od == bd && oc < bc)) { bd = od; bc = oc; }
            }
            if (l16 == 0) {
                unsigned long long key =
                    ((unsigned long long)__builtin_bit_cast(unsigned, bd) << 32) | (unsigned)bc;
                atomicMin(&packed[row], key);
            }
        }
        __syncthreads();
    }
}

// ---------------- K1c: resolve worklist rows -> idx + hist ----------------
__global__ __launch_bounds__(256) void k_resolve(
    const int* __restrict__ wrows, const int* __restrict__ gc,
    const unsigned long long* __restrict__ packed,
    int* __restrict__ idx_out, float* __restrict__ idxf_out, int* __restrict__ hist)
{
    const int nw = gc[0];
    for (int i = blockIdx.x * 256 + threadIdx.x; i < nw; i += gridDim.x * 256) {
        const int row = wrows[i];
        const int c = (int)(packed[row] & 0xffffffffu);
        idx_out[row] = c;
        idxf_out[row] = (float)c;
        atomicAdd(&hist[c], 1);
    }
}

// ---------------- K2: prefix sum of histogram -> offsets + cursors ----------------
__global__ __launch_bounds__(1024) void k_prefix(
    const int* __restrict__ hist, int* __restrict__ offs, int* __restrict__ curs)
{
    __shared__ int tmp[1024];
    const int tid = threadIdx.x;
    const int h = hist[tid];
    tmp[tid] = h;
    __syncthreads();
    for (int off = 1; off < 1024; off <<= 1) {
        int v = (tid >= off) ? tmp[tid - off] : 0;
        __syncthreads();
        tmp[tid] += v;
        __syncthreads();
    }
    int ex = tmp[tid] - h;
    offs[tid] = ex;
    curs[tid] = ex;
}

// ---------------- K3: fill row-id bins ----------------
__global__ __launch_bounds__(256) void k_fill(
    const int* __restrict__ idx_in, int* __restrict__ curs, int* __restrict__ rowids)
{
    int r = blockIdx.x * 256 + threadIdx.x;
    int c = idx_in[r];
    int slot = atomicAdd(&curs[c], 1);
    rowids[slot] = r;
}

// ---------------- K4: per-code dw + quantized gather-write + loss ----------------
__global__ __launch_bounds__(256) void k_dw(
    const float* __restrict__ x, const float* __restrict__ ew,
    const int* __restrict__ hist, const int* __restrict__ offs,
    const int* __restrict__ rowids,
    float* __restrict__ q_out, float* __restrict__ dw, double* __restrict__ lossp)
{
    const int c = blockIdx.x;
    const int tid = threadIdx.x;
    const int n = hist[c];
    const int base = offs[c];
    const float ev = ew[(size_t)c * 256 + tid];
    float acc = 0.f;
    float lsum = 0.f;
    for (int i = 0; i < n; ++i) {
        int row = rowids[base + i];
        float xv = x[(size_t)row * 256 + tid];
        q_out[(size_t)row * 256 + tid] = ev;
        acc += xv;
        float df = ev - xv;
        lsum += df * df;
    }
    dw[(size_t)c * 256 + tid] = acc;
    const int lane = tid & 63, wid = tid >> 6;
    __shared__ float wsum[4];
#pragma unroll
    for (int m = 1; m < 64; m <<= 1) lsum += __shfl_xor(lsum, m);
    if (lane == 0) wsum[wid] = lsum;
    __syncthreads();
    if (tid == 0)
        lossp[c] = (double)wsum[0] + wsum[1] + wsum[2] + wsum[3];
}

// ---------------- K5: finalize new_cs (+ n) and loss ----------------
__global__ __launch_bounds__(1024) void k_finalize(
    const float* __restrict__ ema_cs, const int* __restrict__ hist,
    const double* __restrict__ lossp, float* __restrict__ out)
{
    __shared__ double red[1024];
    const int tid = threadIdx.x;
    float raw = ema_cs[tid] * 0.99f + 0.01f * (float)hist[tid];
    red[tid] = (double)raw;
    __syncthreads();
    for (int s = 512; s > 0; s >>= 1) {
        if (tid < s) red[tid] += red[tid + s];
        __syncthreads();
    }
    double n = red[0];
    __syncthreads();
    float csn = (raw + 1e-5f) * (float)(n / (n + 1024.0 * 1e-5));
    out[OFF_CS + tid] = csn;
    red[tid] = lossp[tid];
    __syncthreads();
    for (int s = 512; s > 0; s >>= 1) {
        if (tid < s) red[tid] += red[tid + s];
        __syncthreads();
    }
    if (tid == 0) out[OFF_LOSS] = (float)(red[0] * 1.25 / 16777216.0);
}

// ---------------- K6: new_ema_w + updated_embed ----------------
__global__ __launch_bounds__(256) void k_ema(
    const float* __restrict__ ema_w, const float* __restrict__ dw,
    const float* __restrict__ cs_out, float* __restrict__ out)
{
    int id = blockIdx.x * 256 + threadIdx.x;
    int k = id >> 8;
    float nw = ema_w[id] * 0.99f + 0.01f * dw[id];
    out[OFF_EMAW + id] = nw;
    out[OFF_UPD + id] = nw / cs_out[k];
}

extern "C" void kernel_launch(void* const* d_in, const int* in_sizes, int n_in,
                              void* d_out, int out_size, void* d_ws, size_t ws_size,
                              hipStream_t stream)
{
    const float* x      = (const float*)d_in[0];
    const float* ew     = (const float*)d_in[1];
    const float* ema_cs = (const float*)d_in[2];
    const float* ema_w  = (const float*)d_in[3];
    float* out = (float*)d_out;
    char* ws = (char*)d_ws;

    int*    hist    = (int*)(ws + WS_HIST);
    int*    offs    = (int*)(ws + WS_OFFS);
    int*    curs    = (int*)(ws + WS_CURS);
    int*    idxi    = (int*)(ws + WS_IDX);
    int*    rowids  = (int*)(ws + WS_ROWIDS);
    int*    wrows   = (int*)(ws + WS_WROWS);
    float*  sqx     = (float*)(ws + WS_SQX);
    float*  sqe     = (float*)(ws + WS_SQE);
    float*  dw      = (float*)(ws + WS_DW);
    unsigned long long* packed = (unsigned long long*)(ws + WS_PACK);
    int*    gc      = (int*)(ws + WS_GCNT);
    double* lossp   = (double*)(ws + WS_LOSSP);
    unsigned short* ebt = (unsigned short*)(ws + WS_EBT);
    unsigned int* plist = (unsigned int*)(ws + WS_PLIST);

    hipMemsetAsync(hist, 0, 4096, stream);
    hipMemsetAsync(packed, 0xFF, 524288, stream);
    hipMemsetAsync(gc, 0, 16, stream);
    hipLaunchKernelGGL(k_sq, dim3(K / 256), dim3(256), 0, stream, ew, sqe, K);
    hipLaunchKernelGGL(k_cvt, dim3(32), dim3(256), 0, stream, ew, ebt);
    hipLaunchKernelGGL(k_screen, dim3(NROWS / 64), dim3(512), 0, stream,
                       x, ebt, sqe, sqx, idxi, out + OFF_IDX, hist, wrows, gc, plist);
    hipLaunchKernelGGL(k_rescore, dim3(2048), dim3(256), 0, stream,
                       x, ew, sqx, sqe, plist, gc, packed);
    hipLaunchKernelGGL(k_resolve, dim3(64), dim3(256), 0, stream,
                       wrows, gc, packed, idxi, out + OFF_IDX, hist);
    hipLaunchKernelGGL(k_prefix, dim3(1), dim3(1024), 0, stream, hist, offs, curs);
    hipLaunchKernelGGL(k_fill, dim3(NROWS / 256), dim3(256), 0, stream,
                       idxi, curs, rowids);
    hipLaunchKernelGGL(k_dw, dim3(K), dim3(256), 0, stream,
                       x, ew, hist, offs, rowids, out + OFF_Q, dw, lossp);
    hipLaunchKernelGGL(k_finalize, dim3(1), dim3(1024), 0, stream,
                       ema_cs, hist, lossp, out);
    hipLaunchKernelGGL(k_ema, dim3(1024), dim3(256), 0, stream,
                       ema_w, dw, out + OFF_CS, out);
}